// Round 6
// baseline (99.901 us; speedup 1.0000x reference)
//
#include <hip/hip_runtime.h>
#include <math.h>

#define BB 64          // batch
#define CC 16          // children per sample
#define DD 512         // feature dim
#define LL 8192        // CC*DD flattened length
#define EPSV 1e-8f
#define INVT 10.0f     // 1/TEMPERATURE
#define NEGINF_T (-1e31f)

// ws layout (bytes):
//  [0,   1 MB)  cib : ci as bf16 [1024][512]
//  [1MB, 2 MB)  cjb : cj as bf16 [1024][512]
//  2MB +0    : n2i [1024] f32 (4 KB)  ||ci row||^2 (fp32 exact)
//      +4 KB : n2j [1024] f32 (4 KB)
//      +8 KB : posrow [1024] f32      per-child-row dot(ci_r, cj_r) (fp32)
//      +12KB : dj [64][64] f32 (16 KB)
//      +28KB : dk [64][64] f32 (16 KB)
//      +44KB : gj [64][64] f32 (16 KB)
//      +60KB : gk [64][64] f32 (16 KB)
//      +76KB : cnt [64] int           per-anchor arrival counters
#define OFF_CIB 0u
#define OFF_CJB (1u << 20)
#define BASE2   (2u << 20)
#define OFF_N2I (BASE2)
#define OFF_N2J (BASE2 + 4096u)
#define OFF_PR  (BASE2 + 8192u)
#define OFF_DJ  (BASE2 + 12288u)
#define OFF_DK  (BASE2 + 28672u)
#define OFF_GJ  (BASE2 + 45056u)
#define OFF_GK  (BASE2 + 61440u)
#define OFF_CNT (BASE2 + 77824u)

typedef short bf16x8 __attribute__((ext_vector_type(8)));
typedef float f32x4  __attribute__((ext_vector_type(4)));

__device__ __forceinline__ float dot4(float4 a, float4 b) {
    return a.x * b.x + a.y * b.y + a.z * b.z + a.w * b.w;
}
__device__ __forceinline__ float wave_reduce(float v) {
    #pragma unroll
    for (int off = 32; off; off >>= 1) v += __shfl_down(v, off);
    return v;
}
__device__ __forceinline__ unsigned short f2bf(float f) {  // RNE bf16
    union { float f; unsigned u; } x; x.f = f;
    return (unsigned short)((x.u + 0x7fffu + ((x.u >> 16) & 1u)) >> 16);
}

// ---------------------------------------------------------------------------
// prep: 256 blocks; wave w owns child-row r = b*4+w (0..1023). Single pass:
// reads ci_r and cj_r once, emits n2i[r], n2j[r], posrow[r] (all fp32-exact)
// and both bf16 rows. Block 0 also zeroes cnt[] and out[0].
// ---------------------------------------------------------------------------
__global__ __launch_bounds__(256) void ntx_prep(const float* __restrict__ ci,
                                                const float* __restrict__ cj,
                                                char* __restrict__ ws,
                                                float* __restrict__ out) {
    const int b = blockIdx.x, tid = threadIdx.x;
    const int wave = tid >> 6, lane = tid & 63;
    const int r = b * 4 + wave;            // 0..1023

    const float4* ci4 = (const float4*)(ci + r * DD);
    const float4* cj4 = (const float4*)(cj + r * DD);
    float4 a1 = ci4[lane], a2 = ci4[64 + lane];
    float4 b1 = cj4[lane], b2 = cj4[64 + lane];

    float ni = wave_reduce(dot4(a1, a1) + dot4(a2, a2));
    float nj = wave_reduce(dot4(b1, b1) + dot4(b2, b2));
    float pd = wave_reduce(dot4(a1, b1) + dot4(a2, b2));
    if (lane == 0) {
        ((float*)(ws + OFF_N2I))[r] = ni;
        ((float*)(ws + OFF_N2J))[r] = nj;
        ((float*)(ws + OFF_PR))[r]  = pd;
    }

    ushort4 hi1 = { f2bf(a1.x), f2bf(a1.y), f2bf(a1.z), f2bf(a1.w) };
    ushort4 hi2 = { f2bf(a2.x), f2bf(a2.y), f2bf(a2.z), f2bf(a2.w) };
    ushort4 hj1 = { f2bf(b1.x), f2bf(b1.y), f2bf(b1.z), f2bf(b1.w) };
    ushort4 hj2 = { f2bf(b2.x), f2bf(b2.y), f2bf(b2.z), f2bf(b2.w) };
    ushort4* di = (ushort4*)((unsigned short*)(ws + OFF_CIB) + r * DD);
    ushort4* dj = (ushort4*)((unsigned short*)(ws + OFF_CJB) + r * DD);
    di[lane] = hi1;  di[64 + lane] = hi2;
    dj[lane] = hj1;  dj[64 + lane] = hj2;

    if (b == 0) {
        if (tid < 64)       ((int*)(ws + OFF_CNT))[tid] = 0;
        else if (tid == 64) out[0] = 0.f;
    }
}

// ---------------------------------------------------------------------------
// strip+final: block b -> (i = b>>2, q = b&3); side = q>>1 (0: cj/dj, 1:
// ci/dk), jh = q&1 (j in [jh*32, jh*32+32)). MFMA computes the 16x512 strip
// S[c][x] = ci_child(i,c) . src_row(jh*512+x) into LDS; gathers dj/gj (or
// dk/gk) for its 32 j's from LDS; the last of the 4 blocks for anchor i
// (device-scope counter) runs the masked logsumexp and atomicAdds the loss.
// Fragment layouts (HW-verified): A/B lane l: row l&15, k=(l>>4)*8..+7;
// C/D: col(n)=l&15, row(m)=(l>>4)*4+reg.
// ---------------------------------------------------------------------------
__global__ __launch_bounds__(256) void ntx_strip(const int* __restrict__ nj,
                                                 const int* __restrict__ nk,
                                                 const int* __restrict__ pids,
                                                 char* __restrict__ ws,
                                                 float* __restrict__ out) {
    const int b = blockIdx.x;          // 0..255
    const int i = b >> 2, q = b & 3;
    const int side = q >> 1, jh = q & 1;
    const int tid  = threadIdx.x;
    const int wave = tid >> 6, lane = tid & 63;
    const int quad = lane >> 4, lr = lane & 15;

    __shared__ float sS[16][512];      // 32 KB strip
    __shared__ int   sOld;

    const short* A  = (const short*)(ws + OFF_CIB) + i * CC * DD;
    const short* Bm = (const short*)(ws + (side ? OFF_CIB : OFF_CJB)) + jh * 512 * DD;

    f32x4 acc[8] = {};
    #pragma unroll
    for (int kk = 0; kk < 16; ++kk) {
        const int k = kk * 32 + quad * 8;
        bf16x8 av = *(const bf16x8*)(A + lr * DD + k);
        #pragma unroll
        for (int tt = 0; tt < 8; ++tt) {
            const int row = (wave * 8 + tt) * 16 + lr;   // source row in half
            bf16x8 bv = *(const bf16x8*)(Bm + row * DD + k);
            acc[tt] = __builtin_amdgcn_mfma_f32_16x16x32_bf16(av, bv, acc[tt], 0, 0, 0);
        }
    }
    #pragma unroll
    for (int tt = 0; tt < 8; ++tt) {
        const int t = wave * 8 + tt;
        #pragma unroll
        for (int r = 0; r < 4; ++r)
            sS[quad * 4 + r][t * 16 + lr] = acc[tt][r];
    }
    __syncthreads();

    // gather: 8 threads per j (32 j's), 2 children per thread
    {
        const int jj = tid >> 3;           // 0..31 local j
        const int g  = tid & 7;
        const int j  = jh * 32 + jj;
        const int* idxp = (side ? nk : nj) + (i * BB + j) * CC;
        const float* n2 = (const float*)(ws + (side ? OFF_N2I : OFF_N2J)) + j * CC;
        const int c0 = g * 2;
        const int x0 = idxp[c0], x1 = idxp[c0 + 1];
        float d  = sS[c0][jj * 16 + x0] + sS[c0 + 1][jj * 16 + x1];
        float gn = n2[x0] + n2[x1];
        d += __shfl_down(d, 4);  gn += __shfl_down(gn, 4);
        d += __shfl_down(d, 2);  gn += __shfl_down(gn, 2);
        d += __shfl_down(d, 1);  gn += __shfl_down(gn, 1);
        if (g == 0) {
            ((float*)(ws + (side ? OFF_DK : OFF_DJ)))[i * BB + j] = d;
            ((float*)(ws + (side ? OFF_GK : OFF_GJ)))[i * BB + j] = gn;
        }
    }

    // last-block-per-anchor fused final
    __threadfence();
    __syncthreads();
    if (tid == 0) sOld = atomicAdd((int*)(ws + OFF_CNT) + i, 1);
    __syncthreads();
    if (sOld == 3 && tid < 64) {
        const int j = tid;                 // wave 0 exactly
        __threadfence();
        float* DJ = (float*)(ws + OFF_DJ);
        float* DK = (float*)(ws + OFF_DK);
        float* GJ = (float*)(ws + OFF_GJ);
        float* GK = (float*)(ws + OFF_GK);
        // atomic reads: device-coherent across XCDs
        const float dj = atomicAdd(DJ + i * BB + j, 0.f);
        const float dk = atomicAdd(DK + i * BB + j, 0.f);
        const float gj = atomicAdd(GJ + i * BB + j, 0.f);
        const float gk = atomicAdd(GK + i * BB + j, 0.f);

        const float* n2i = (const float*)(ws + OFF_N2I);
        const float* n2j = (const float*)(ws + OFF_N2J);
        const float* pr  = (const float*)(ws + OFF_PR);
        float si = 0.f, sjf = 0.f, pos = 0.f;
        #pragma unroll
        for (int c = 0; c < CC; ++c) {
            si  += n2i[i * CC + c];
            sjf += n2j[i * CC + c];
            pos += pr[i * CC + c];
        }
        const float ni = fmaxf(sqrtf(si), EPSV);
        const float l0 = pos / (ni * fmaxf(sqrtf(sjf), EPSV)) * INVT;

        const bool valid = (j != i) && (pids[j] != pids[i]);
        float lj = NEGINF_T, lk = NEGINF_T;
        if (valid) {
            const float inv = INVT / ni;
            lj = dj / fmaxf(sqrtf(gj), EPSV) * inv;
            lk = dk / fmaxf(sqrtf(gk), EPSV) * inv;
        }

        float m = fmaxf(lj, lk);
        #pragma unroll
        for (int off = 32; off; off >>= 1) m = fmaxf(m, __shfl_xor(m, off));
        m = fmaxf(m, l0);

        float s = __expf(lj - m) + __expf(lk - m);
        #pragma unroll
        for (int off = 32; off; off >>= 1) s += __shfl_down(s, off);
        if (j == 0) {
            s += __expf(l0 - m);
            const float loss_i = -l0 + m + __logf(s);
            atomicAdd(out, loss_i * (1.0f / (2.0f * BB)));
        }
    }
}

// ---------------------------------------------------------------------------
extern "C" void kernel_launch(void* const* d_in, const int* in_sizes, int n_in,
                              void* d_out, int out_size, void* d_ws, size_t ws_size,
                              hipStream_t stream) {
    const float* ci  = (const float*)d_in[0];
    const float* cj  = (const float*)d_in[1];
    const int*  pids = (const int*) d_in[2];
    const int*  nj   = (const int*) d_in[3];
    const int*  nk   = (const int*) d_in[4];
    char*  ws  = (char*)d_ws;
    float* out = (float*)d_out;

    ntx_prep<<<256, 256, 0, stream>>>(ci, cj, ws, out);
    ntx_strip<<<256, 256, 0, stream>>>(nj, nk, pids, ws, out);
}